// Round 3
// baseline (63.721 us; speedup 1.0000x reference)
//
#include <hip/hip_runtime.h>
#include <math.h>

#define LAYERS  3
#define PATCHES 196   // 14*14

// Factorized 4-qubit circuit: gate set {RX(w), CNOT(0,1), CNOT(2,3), RZ(w)}
// never couples pair (0,1) with (2,3) -> state is always psi_A (x) psi_B, two
// independent 2-qubit (4-amplitude) circuits; <Z_0,1> from psi_A, <Z_2,3> from
// psi_B.
//
// RZ diagonal per pair per layer has only 2 distinct angles:
//   S=(phi_u+phi_v)/2, D=(phi_u-phi_v)/2
// The 12 (c,s) pairs are uniform across the block -> built into LDS by idle
// wave-3 threads, overlapped with patch threads' pixel loads + sincos.
//
// Latency pipelining (this round): the 10 W float4 loads and the bias load are
// issued at the TOP of the kernel (unconditional, clamped index) so their
// ~900-cycle cold-HBM latency overlaps the circuit compute, instead of being
// issued after the circuit where they serially extend the critical path.
// Lanes >=196 have z=0, so their linear-layer contributions vanish through the
// FMAs -- no guard branch needed around the epilogue math.

__device__ __forceinline__ void pair_layer(
    float r[4], float im[4],
    float cu, float su, float cv, float sv,
    float cS, float sS, float cD, float sD)
{
    // RX on u (high bit): butterflies (0,2),(1,3); new = c*a - i*s*a'
    {
        float t0r=r[0], t0i=im[0], t1r=r[2], t1i=im[2];
        r[0]=fmaf(cu,t0r, su*t1i); im[0]=fmaf(cu,t0i,-su*t1r);
        r[2]=fmaf(cu,t1r, su*t0i); im[2]=fmaf(cu,t1i,-su*t0r);
    }
    {
        float t0r=r[1], t0i=im[1], t1r=r[3], t1i=im[3];
        r[1]=fmaf(cu,t0r, su*t1i); im[1]=fmaf(cu,t0i,-su*t1r);
        r[3]=fmaf(cu,t1r, su*t0i); im[3]=fmaf(cu,t1i,-su*t0r);
    }
    // RX on v (low bit): butterflies (0,1),(2,3)
    {
        float t0r=r[0], t0i=im[0], t1r=r[1], t1i=im[1];
        r[0]=fmaf(cv,t0r, sv*t1i); im[0]=fmaf(cv,t0i,-sv*t1r);
        r[1]=fmaf(cv,t1r, sv*t0i); im[1]=fmaf(cv,t1i,-sv*t0r);
    }
    {
        float t0r=r[2], t0i=im[2], t1r=r[3], t1i=im[3];
        r[2]=fmaf(cv,t0r, sv*t1i); im[2]=fmaf(cv,t0i,-sv*t1r);
        r[3]=fmaf(cv,t1r, sv*t0i); im[3]=fmaf(cv,t1i,-sv*t0r);
    }
    // CNOT(u,v): swap indices 2,3 (register rename, free)
    { float tr=r[2]; r[2]=r[3]; r[3]=tr; float ti=im[2]; im[2]=im[3]; im[3]=ti; }
    // RZ diagonal
    {
        float rr, ii;
        rr=r[0]; ii=im[0];  r[0]=fmaf(rr,cS,  ii*sS); im[0]=fmaf(ii,cS, -rr*sS);
        rr=r[1]; ii=im[1];  r[1]=fmaf(rr,cD,  ii*sD); im[1]=fmaf(ii,cD, -rr*sD);
        rr=r[2]; ii=im[2];  r[2]=fmaf(rr,cD, -ii*sD); im[2]=fmaf(ii,cD,  rr*sD);
        rr=r[3]; ii=im[3];  r[3]=fmaf(rr,cS, -ii*sS); im[3]=fmaf(ii,cS,  rr*sS);
    }
}

__global__ __launch_bounds__(256) void quanv_fused(
    const float* __restrict__ x,     // [B,1,28,28]
    const float* __restrict__ qp,    // [LAYERS,WIRES]
    const float* __restrict__ Wt,    // [10,784]
    const float* __restrict__ bias,  // [10]
    float* __restrict__ out)         // [B,10]
{
    __shared__ float2 ph[LAYERS * 4];   // [(l*2+p)*2+d] = (cos, sin); d: 0=S 1=D
    __shared__ float wsum[4][10];

    const int b = blockIdx.x;
    const int t = threadIdx.x;

    // ---- issue ALL epilogue global loads up front (overlap with compute) ----
    const int p0 = t & ~1;                         // even patch of the pair
    const int p0c = (p0 > 194) ? 194 : p0;         // clamp for lanes >=196
    const int kbase = (t & 1) * 5;
    const float4* W4 = reinterpret_cast<const float4*>(Wt);  // [10][196]
    float4 w0r[5], w1r[5];
    #pragma unroll
    for (int k = 0; k < 5; ++k) {
        w0r[k] = W4[(kbase + k) * 196 + p0c];
        w1r[k] = W4[(kbase + k) * 196 + p0c + 1];
    }
    const float bv = (t < 10) ? bias[t] : 0.f;

    // ---- RZ phase table: 12 sincos on idle wave-3 threads ----
    if (t >= 208 && t < 208 + LAYERS * 4) {
        const int j = t - 208;                     // j = l*4 + p*2 + d
        const int l = j >> 2, p = (j >> 1) & 1, d = j & 1;
        const float pu = qp[l*4 + 2*p], pv = qp[l*4 + 2*p + 1];
        float s, c;
        __sincosf(0.5f * (d ? (pu - pv) : (pu + pv)), &s, &c);
        ph[j] = make_float2(c, s);
    }

    // ---- patch pixel loads + RX sincos (overlaps table build) ----
    float cw[4], sw[4];
    if (t < PATCHES) {
        const int r = t / 14, cc = t % 14;
        const float* xb = x + (size_t)b * 784;
        const float2 top = *reinterpret_cast<const float2*>(xb + (2*r)*28 + 2*cc);
        const float2 bot = *reinterpret_cast<const float2*>(xb + (2*r+1)*28 + 2*cc);
        __sincosf(0.5f * top.x, &sw[0], &cw[0]);   // tl -> wire 0
        __sincosf(0.5f * top.y, &sw[1], &cw[1]);   // tr -> wire 1
        __sincosf(0.5f * bot.x, &sw[2], &cw[2]);   // bl -> wire 2
        __sincosf(0.5f * bot.y, &sw[3], &cw[3]);   // br -> wire 3
    }
    __syncthreads();

    float z[4] = {0.f, 0.f, 0.f, 0.f};
    if (t < PATCHES) {
        // ---- layer 1 analytic: amp_i = m_i * (-i)^popcount(i); CNOT perm
        //      (2<->3) and RZ[0] diagonal folded in ----
        float Ar[4], Ai[4], Br[4], Bi[4];
        {
            const float m0=cw[0]*cw[1], m1=cw[0]*sw[1], m2=sw[0]*cw[1], m3=sw[0]*sw[1];
            const float cs=ph[0].x, ss=ph[0].y, cd=ph[1].x, sd=ph[1].y;
            Ar[0]= m0*cs;  Ai[0]=-m0*ss;   // i=0 -> ti=0, pc=0
            Ar[1]=-m1*sd;  Ai[1]=-m1*cd;   // i=1 -> ti=1, pc=1
            Ar[3]= m2*ss;  Ai[3]=-m2*cs;   // i=2 -> ti=3, pc=1
            Ar[2]=-m3*cd;  Ai[2]=-m3*sd;   // i=3 -> ti=2, pc=2
        }
        {
            const float m0=cw[2]*cw[3], m1=cw[2]*sw[3], m2=sw[2]*cw[3], m3=sw[2]*sw[3];
            const float cs=ph[2].x, ss=ph[2].y, cd=ph[3].x, sd=ph[3].y;
            Br[0]= m0*cs;  Bi[0]=-m0*ss;
            Br[1]=-m1*sd;  Bi[1]=-m1*cd;
            Br[3]= m2*ss;  Bi[3]=-m2*cs;
            Br[2]=-m3*cd;  Bi[2]=-m3*sd;
        }

        // ---- layers 2..3: two independent 2-qubit circuits ----
        #pragma unroll
        for (int l = 1; l < LAYERS; ++l) {
            pair_layer(Ar, Ai, cw[0],sw[0], cw[1],sw[1],
                       ph[l*4+0].x, ph[l*4+0].y, ph[l*4+1].x, ph[l*4+1].y);
            pair_layer(Br, Bi, cw[2],sw[2], cw[3],sw[3],
                       ph[l*4+2].x, ph[l*4+2].y, ph[l*4+3].x, ph[l*4+3].y);
        }

        // ---- <Z_w> ----
        {
            const float p0a=fmaf(Ar[0],Ar[0],Ai[0]*Ai[0]);
            const float p1a=fmaf(Ar[1],Ar[1],Ai[1]*Ai[1]);
            const float p2a=fmaf(Ar[2],Ar[2],Ai[2]*Ai[2]);
            const float p3a=fmaf(Ar[3],Ar[3],Ai[3]*Ai[3]);
            z[0] = (p0a+p1a) - (p2a+p3a);   // wire 0 = high bit of pair A
            z[1] = (p0a+p2a) - (p1a+p3a);   // wire 1 = low bit
        }
        {
            const float p0b=fmaf(Br[0],Br[0],Bi[0]*Bi[0]);
            const float p1b=fmaf(Br[1],Br[1],Bi[1]*Bi[1]);
            const float p2b=fmaf(Br[2],Br[2],Bi[2]*Bi[2]);
            const float p3b=fmaf(Br[3],Br[3],Bi[3]*Bi[3]);
            z[2] = (p0b+p1b) - (p2b+p3b);   // wire 2
            z[3] = (p0b+p2b) - (p1b+p3b);   // wire 3
        }
    }

    // ---- linear layer: lane-parity class split over patch pairs ----
    // Exchange z with xor-1 neighbor; even lane computes classes 0-4 for
    // patches (t, t+1), odd lane classes 5-9 for the same pair. Lanes >=196
    // carry z=0 so their contributions vanish -- no guard needed.
    float oz[4];
    #pragma unroll
    for (int j = 0; j < 4; ++j) oz[j] = __shfl_xor(z[j], 1, 64);

    const float* zp0 = (t & 1) ? oz : z;    // z of patch p0
    const float* zp1 = (t & 1) ? z : oz;    // z of patch p0+1
    float part[5];
    #pragma unroll
    for (int k = 0; k < 5; ++k) {
        const float4 w0 = w0r[k];
        const float4 w1 = w1r[k];
        float acc;
        acc = fmaf(zp0[0], w0.x, fmaf(zp0[1], w0.y, fmaf(zp0[2], w0.z, zp0[3] * w0.w)));
        acc = fmaf(zp1[0], w1.x, fmaf(zp1[1], w1.y, fmaf(zp1[2], w1.z, fmaf(zp1[3], w1.w, acc))));
        part[k] = acc;
    }
    // butterfly over offsets 2..32 keeps even/odd (class-group) lanes separate
    #pragma unroll
    for (int k = 0; k < 5; ++k) {
        #pragma unroll
        for (int off = 2; off <= 32; off <<= 1)
            part[k] += __shfl_xor(part[k], off, 64);
    }
    const int wave = t >> 6, lane = t & 63;
    if (lane < 2) {
        #pragma unroll
        for (int k = 0; k < 5; ++k) wsum[wave][lane * 5 + k] = part[k];
    }
    __syncthreads();

    // ---- cross-wave sum + log-softmax on 16 lanes (no second barrier) ----
    if (t < 16) {
        const float v = (t < 10)
            ? (bv + wsum[0][t] + wsum[1][t] + wsum[2][t] + wsum[3][t])
            : -1e30f;
        float mx = v;
        #pragma unroll
        for (int off = 8; off > 0; off >>= 1)
            mx = fmaxf(mx, __shfl_xor(mx, off, 16));
        float se = (t < 10) ? expf(v - mx) : 0.f;
        #pragma unroll
        for (int off = 8; off > 0; off >>= 1)
            se += __shfl_xor(se, off, 16);
        if (t < 10)
            out[b * 10 + t] = v - (mx + logf(se));
    }
}

extern "C" void kernel_launch(void* const* d_in, const int* in_sizes, int n_in,
                              void* d_out, int out_size, void* d_ws, size_t ws_size,
                              hipStream_t stream) {
    const float* x    = (const float*)d_in[0];
    const float* qp   = (const float*)d_in[1];
    const float* W    = (const float*)d_in[2];
    const float* bias = (const float*)d_in[3];
    float* out = (float*)d_out;

    const int B = in_sizes[0] / 784;  // 1024
    quanv_fused<<<B, 256, 0, stream>>>(x, qp, W, bias, out);
}